// Round 11
// baseline (349.818 us; speedup 1.0000x reference)
//
#include <hip/hip_runtime.h>

typedef unsigned short u16;
typedef u16   u16x4 __attribute__((ext_vector_type(4)));
typedef u16   u16x8 __attribute__((ext_vector_type(8)));
typedef short s16x8 __attribute__((ext_vector_type(8)));
typedef float f32x4 __attribute__((ext_vector_type(4)));

__device__ __forceinline__ float b2f(u16 u) {
    return __uint_as_float(((unsigned)u) << 16);
}
__device__ __forceinline__ u16 f2b(float f) {
    unsigned x = __float_as_uint(f);
    x += 0x7fffu + ((x >> 16) & 1u);
    return (u16)(x >> 16);
}
// async global->LDS, 16B per lane; LDS dest = wave-uniform base + lane*16
__device__ __forceinline__ void gload_lds(const u16* g, u16* l) {
    __builtin_amdgcn_global_load_lds(
        (const __attribute__((address_space(1))) unsigned int*)g,
        (__attribute__((address_space(3))) unsigned int*)l, 16, 0, 0);
}

#define THETA_SCALE 0.05190512648261f   // log2(10000)/256

// ---------------- prep: Xb = bf16(x) + WT = bf16(Wqk^T) + zero kvbuf/ksum ---
__global__ __launch_bounds__(256)
void k_prep(const float* __restrict__ X, u16* __restrict__ Xb,
            const float* __restrict__ W, u16* __restrict__ WT,
            float* __restrict__ kvz) {
    if (blockIdx.x < 4096) {
        size_t i = (size_t)(blockIdx.x * 256 + threadIdx.x) * 8;
        float4 a = *(const float4*)(X + i);
        float4 b = *(const float4*)(X + i + 4);
        u16x8 r;
        r[0] = f2b(a.x); r[1] = f2b(a.y); r[2] = f2b(a.z); r[3] = f2b(a.w);
        r[4] = f2b(b.x); r[5] = f2b(b.y); r[6] = f2b(b.z); r[7] = f2b(b.w);
        *(u16x8*)(Xb + i) = r;
    } else if (blockIdx.x < 4608) {
        __shared__ float tile[32][33];
        int bid = blockIdx.x - 4096;        // 0..511 = 32 x 16
        int c0 = (bid & 31) * 32;
        int r0 = (bid >> 5) * 32;
        int tx = threadIdx.x & 31;
        int ty = threadIdx.x >> 5;
        #pragma unroll
        for (int i = 0; i < 4; ++i) {
            int r = ty + i * 8;
            tile[r][tx] = W[(size_t)(r0 + r) * 1024 + c0 + tx];
        }
        __syncthreads();
        #pragma unroll
        for (int i = 0; i < 4; ++i) {
            int r = ty + i * 8;
            WT[(size_t)(c0 + r) * 512 + r0 + tx] = f2b(tile[tx][r]);
        }
    } else {
        // zero kvbuf (65536 f) + ksum (2048 f): 66 blocks x 1024 floats
        size_t i = (size_t)(blockIdx.x - 4608) * 1024 + threadIdx.x * 4;
        *(float4*)(kvz + i) = make_float4(0.f, 0.f, 0.f, 0.f);
    }
}

// ---------------- GEMM + fused kv/ksum epilogue -----------------------------
// Q-blocks (n0<512): bias+elu+1 -> Qb (bf16).
// K-blocks (n0>=512): bias+elu+1 -> ksum atomics; rope in-register (shfl_xor
// partner); krT/vT col-major XOR-swizzled LDS; kv via 16x16x32 MFMA;
// atomicAdd into kvbuf. Kb never materialized.
__global__ __launch_bounds__(256)
void k_gemm(const u16* __restrict__ Xb, const u16* __restrict__ WT,
            const float* __restrict__ bqk, u16* __restrict__ Qb,
            float* __restrict__ kvbuf, float* __restrict__ ksum) {
    __shared__ u16 shm[128 * 128];       // main: As=[0,8K), Bs=[8K,16K); epi: krT
    __shared__ u16 vTs[32 * 128];        // per-head v, col-major swizzled
    __shared__ float ksl[128];
    u16* As = shm;
    u16* Bs = shm + 128 * 64;
    const int t = threadIdx.x;
    const int m0 = blockIdx.x * 128;
    const int n0 = blockIdx.y * 128;
    const int lane = t & 63;
    const int wave = t >> 6;
    const int wm = (wave >> 1) * 64;
    const int wn = (wave & 1) * 64;
    const int quad = lane >> 4;
    const int l16 = lane & 15;
    const int lr = lane >> 3;
    const int cg = ((lane & 7) ^ lr) * 8;

    f32x4 acc[4][4];
    f32x4 zero4 = {0.f, 0.f, 0.f, 0.f};
    #pragma unroll
    for (int i = 0; i < 4; ++i)
        #pragma unroll
        for (int j = 0; j < 4; ++j) acc[i][j] = zero4;

    for (int k0 = 0; k0 < 512; k0 += 64) {
        __syncthreads();
        #pragma unroll
        for (int g = 0; g < 4; ++g) {
            int r0 = wave * 32 + g * 8;
            size_t ga = (size_t)(m0 + r0 + lr) * 512 + k0 + cg;
            size_t gb = (size_t)(n0 + r0 + lr) * 512 + k0 + cg;
            gload_lds(Xb + ga, &As[r0 * 64]);
            gload_lds(WT + gb, &Bs[r0 * 64]);
        }
        __syncthreads();
        #pragma unroll
        for (int ks = 0; ks < 64; ks += 32) {
            const int cbase = quad + (ks >> 3);
            s16x8 a4[4], b4[4];
            #pragma unroll
            for (int i = 0; i < 4; ++i) {
                int row = wm + i * 16 + l16;
                a4[i] = *(const s16x8*)&As[row * 64 + ((cbase ^ (row & 7)) * 8)];
            }
            #pragma unroll
            for (int j = 0; j < 4; ++j) {
                int row = wn + j * 16 + l16;
                b4[j] = *(const s16x8*)&Bs[row * 64 + ((cbase ^ (row & 7)) * 8)];
            }
            #pragma unroll
            for (int i = 0; i < 4; ++i)
                #pragma unroll
                for (int j = 0; j < 4; ++j)
                    acc[i][j] = __builtin_amdgcn_mfma_f32_16x16x32_bf16(
                        a4[i], b4[j], acc[i][j], 0, 0, 0);
        }
    }

    if (n0 < 512) {
        // ---------------- Q epilogue (unchanged) ----------------
        #pragma unroll
        for (int i = 0; i < 4; ++i)
            #pragma unroll
            for (int j = 0; j < 4; ++j) {
                int col = n0 + wn + j * 16 + l16;
                float bias = bqk[col];
                #pragma unroll
                for (int r = 0; r < 4; ++r) {
                    int grow = m0 + wm + i * 16 + quad * 4 + r;
                    float v = acc[i][j][r] + bias;
                    v = v > 0.f ? v + 1.f : __expf(v);
                    Qb[(size_t)grow * 512 + col] = f2b(v);
                }
            }
        return;
    }

    // ---------------- K epilogue: ksum + rope + fused kv --------------------
    const int batch = m0 >> 12;          // 4096-row batches
    const int h0 = (n0 - 512) >> 5;      // first head of this block
    if (t < 128) ksl[t] = 0.f;

    // k = elu(qk)+1 in place; per-column partial sums
    float csum[4];
    #pragma unroll
    for (int j = 0; j < 4; ++j) {
        int gc = (n0 - 512) + wn + j * 16 + l16;
        float bias = bqk[gc + 512];
        float s = 0.f;
        #pragma unroll
        for (int i = 0; i < 4; ++i)
            #pragma unroll
            for (int r = 0; r < 4; ++r) {
                float v = acc[i][j][r] + bias;
                v = v > 0.f ? v + 1.f : __expf(v);
                acc[i][j][r] = v;
                s += v;
            }
        csum[j] = s;
    }
    __syncthreads();   // main-loop LDS reads done + ksl zero visible
    #pragma unroll
    for (int j = 0; j < 4; ++j)
        atomicAdd(&ksl[wn + j * 16 + l16], csum[j]);

    // rope in place: partner via shfl_xor(1); theta from global pair index
    const int evenlane = (l16 & 1) == 0;
    #pragma unroll
    for (int j = 0; j < 4; ++j) {
        int gc = (n0 - 512) + wn + j * 16 + l16;
        float th = exp2f(-THETA_SCALE * (float)(gc >> 1));
        #pragma unroll
        for (int i = 0; i < 4; ++i)
            #pragma unroll
            for (int r = 0; r < 4; ++r) {
                int n = ((m0 + wm + i * 16 + quad * 4 + r) & 4095);
                float k = acc[i][j][r];
                float p = __shfl_xor(k, 1);
                float sv, cv;
                sincosf((float)n * th, &sv, &cv);
                acc[i][j][r] = evenlane ? (k * cv - p * sv) : (p * sv + k * cv);
            }
    }

    // write krT[col][row] bf16, XOR-swizzled 8-u16 chunks
    #pragma unroll
    for (int j = 0; j < 4; ++j) {
        int lc = wn + j * 16 + l16;
        #pragma unroll
        for (int i = 0; i < 4; ++i) {
            int rowb = wm + i * 16 + quad * 4;
            int phys = lc * 128 + (((rowb >> 3) ^ (lc & 7)) << 3) + (rowb & 7);
            u16x4 w4;
            w4[0] = f2b(acc[i][j][0]); w4[1] = f2b(acc[i][j][1]);
            w4[2] = f2b(acc[i][j][2]); w4[3] = f2b(acc[i][j][3]);
            *(u16x4*)&shm[phys] = w4;
        }
    }
    __syncthreads();

    // ksum -> global
    if (t < 128) {
        int gc = (n0 - 512) + t;
        atomicAdd(&ksum[(batch * 16 + (gc >> 5)) * 32 + (gc & 31)], ksl[t]);
    }

    // per-head kv: stage vT, 4 MFMAs/wave (wave = k-chunk), atomic kvbuf
    const int vrow = t >> 1;
    const int vhalf = (t & 1) * 16;
    for (int hh = 0; hh < 4; ++hh) {
        if (hh) __syncthreads();
        // stage vTs[e][row] from Xb rows m0.., channels (n0-512)+hh*32+e
        {
            size_t gb = (size_t)(m0 + vrow) * 512 + (n0 - 512) + hh * 32 + vhalf;
            u16x8 v0 = *(const u16x8*)(Xb + gb);
            u16x8 v1 = *(const u16x8*)(Xb + gb + 8);
            #pragma unroll
            for (int jj = 0; jj < 8; ++jj) {
                int e0 = vhalf + jj, e1 = vhalf + 8 + jj;
                vTs[e0 * 128 + (((vrow >> 3) ^ (e0 & 7)) << 3) + (vrow & 7)] = v0[jj];
                vTs[e1 * 128 + (((vrow >> 3) ^ (e1 & 7)) << 3) + (vrow & 7)] = v1[jj];
            }
        }
        __syncthreads();
        const int bh = batch * 16 + h0 + hh;
        #pragma unroll
        for (int dt = 0; dt < 2; ++dt) {
            int ac = hh * 32 + dt * 16 + l16;          // krT col
            s16x8 a4 = *(const s16x8*)
                &shm[ac * 128 + ((((wave * 4 + quad)) ^ (ac & 7)) << 3)];
            #pragma unroll
            for (int et = 0; et < 2; ++et) {
                int bc = et * 16 + l16;                // vTs col
                s16x8 b4 = *(const s16x8*)
                    &vTs[bc * 128 + ((((wave * 4 + quad)) ^ (bc & 7)) << 3)];
                f32x4 kvq = __builtin_amdgcn_mfma_f32_16x16x32_bf16(
                    a4, b4, zero4, 0, 0, 0);
                #pragma unroll
                for (int r = 0; r < 4; ++r)
                    atomicAdd(&kvbuf[(size_t)bh * 1024 +
                                     (dt * 16 + quad * 4 + r) * 32 + et * 16 + l16],
                              kvq[r]);
            }
        }
    }
}

// ---------------- out = z * (q_rope @ kv)/N + lepe (f32 to d_out) -----------
__global__ __launch_bounds__(256)
void k_out(const u16* __restrict__ Qb, const u16* __restrict__ Xb,
           const float* __restrict__ kvbuf, const float* __restrict__ ksum,
           const float* __restrict__ lw, const float* __restrict__ lb,
           float* __restrict__ OUT) {
    const int b = blockIdx.x >> 6;
    const int nb = (blockIdx.x & 63) * 64;
    const int hbase = blockIdx.y * 4;
    __shared__ float kv_s[32 * 36];
    __shared__ float qr_s[64 * 36];
    __shared__ float ks_s[32];
    __shared__ float z_s[64];
    const int t = threadIdx.x;
    const int row = t >> 2;          // 0..63 local n
    const int c4 = t & 3;
    const int e0 = c4 * 8;
    const float invN = 1.f / 4096.f;
    const int n = nb + row;
    const size_t rowbase = (size_t)(b * 4096 + n) * 512;

    for (int hh = 0; hh < 4; ++hh) {
        const int h = hbase + hh;
        const int bh = b * 16 + h;
        if (hh) __syncthreads();               // protect LDS reuse
        #pragma unroll
        for (int i = 0; i < 4; ++i) {
            int id = t + i * 256;              // 0..1023
            kv_s[(id >> 5) * 36 + (id & 31)] = kvbuf[(size_t)bh * 1024 + id] * invN;
        }
        if (t < 32) ks_s[t] = ksum[bh * 32 + t] * invN;   // kmean
        __syncthreads();

        // phase 1: q (bf16), z partial dot, rope, stage q_rope
        u16x8 q8 = *(const u16x8*)(Qb + rowbase + h * 32 + e0);
        float qf[8];
        #pragma unroll
        for (int j = 0; j < 8; ++j) qf[j] = b2f(q8[j]);
        float part = 0.f;
        #pragma unroll
        for (int j = 0; j < 8; ++j) part += qf[j] * ks_s[e0 + j];
        float qr[8];
        #pragma unroll
        for (int p = 0; p < 4; ++p) {
            float th = exp2f(-THETA_SCALE * (float)(h * 16 + c4 * 4 + p));
            float sv, cv;
            sincosf((float)n * th, &sv, &cv);
            qr[2 * p]     = qf[2 * p] * cv - qf[2 * p + 1] * sv;
            qr[2 * p + 1] = qf[2 * p] * sv + qf[2 * p + 1] * cv;
        }
        *(float4*)&qr_s[row * 36 + e0]     = make_float4(qr[0], qr[1], qr[2], qr[3]);
        *(float4*)&qr_s[row * 36 + e0 + 4] = make_float4(qr[4], qr[5], qr[6], qr[7]);
        part += __shfl_xor(part, 1);
        part += __shfl_xor(part, 2);
        if (c4 == 0) z_s[row] = 1.f / (part + 1e-6f);
        __syncthreads();

        // phase 2: out[e0..e0+7] = z * sum_d qr[d]*kv[d][e]
        float o[8] = {0, 0, 0, 0, 0, 0, 0, 0};
        #pragma unroll 4
        for (int dd = 0; dd < 32; ++dd) {
            float qd = qr_s[row * 36 + dd];
            const float4 k0v = *(const float4*)&kv_s[dd * 36 + e0];
            const float4 k1v = *(const float4*)&kv_s[dd * 36 + e0 + 4];
            o[0] += qd * k0v.x; o[1] += qd * k0v.y; o[2] += qd * k0v.z; o[3] += qd * k0v.w;
            o[4] += qd * k1v.x; o[5] += qd * k1v.y; o[6] += qd * k1v.z; o[7] += qd * k1v.w;
        }
        const float z = z_s[row];

        // lepe: depthwise conv k=3, pad 1 (per-batch), + bias; x via Xb bf16
        const int cb = h * 32 + e0;
        u16x8 xc = *(const u16x8*)(Xb + rowbase + cb);
        u16x8 xm = {0, 0, 0, 0, 0, 0, 0, 0};
        u16x8 xp = {0, 0, 0, 0, 0, 0, 0, 0};
        if (n > 0)    xm = *(const u16x8*)(Xb + rowbase - 512 + cb);
        if (n < 4095) xp = *(const u16x8*)(Xb + rowbase + 512 + cb);
        float rv[8];
        #pragma unroll
        for (int j = 0; j < 8; ++j) {
            int c = cb + j;
            float lep = b2f(xm[j]) * lw[c * 3] +
                        b2f(xc[j]) * lw[c * 3 + 1] +
                        b2f(xp[j]) * lw[c * 3 + 2] + lb[c];
            rv[j] = o[j] * z + lep;
        }
        float* Of = OUT + rowbase + cb;
        *(float4*)Of       = make_float4(rv[0], rv[1], rv[2], rv[3]);
        *(float4*)(Of + 4) = make_float4(rv[4], rv[5], rv[6], rv[7]);
    }
}

extern "C" void kernel_launch(void* const* d_in, const int* in_sizes, int n_in,
                              void* d_out, int out_size, void* d_ws, size_t ws_size,
                              hipStream_t stream) {
    const float* x   = (const float*)d_in[0];
    const float* Wqk = (const float*)d_in[1];
    const float* bqk = (const float*)d_in[2];
    const float* lw  = (const float*)d_in[3];
    const float* lb  = (const float*)d_in[4];
    float* out = (float*)d_out;

    // workspace (~33.3 MB); kvbuf+ksum contiguous (zeroed by k_prep tail)
    char* w = (char*)d_ws;
    u16* Qb      = (u16*)w;   w += (size_t)16384 * 512 * 2;   // 16 MB
    u16* Xb      = (u16*)w;   w += (size_t)16384 * 512 * 2;   // 16 MB
    u16* WT      = (u16*)w;   w += (size_t)1024 * 512 * 2;    // 1 MB
    float* kvbuf = (float*)w; w += (size_t)64 * 1024 * 4;     // 256 KB
    float* ksum  = (float*)w;                                 // 8 KB (contig)

    k_prep<<<4674, 256, 0, stream>>>(x, Xb, Wqk, WT, kvbuf);
    k_gemm<<<dim3(128, 8), 256, 0, stream>>>(Xb, WT, bqk, Qb, kvbuf, ksum);
    k_out<<<dim3(256, 4), 256, 0, stream>>>(Qb, Xb, kvbuf, ksum, lw, lb, out);
}